// Round 1
// baseline (234.165 us; speedup 1.0000x reference)
//
#include <hip/hip_runtime.h>
#include <stdint.h>

#define NN 100000
#define NE 1600000
#define DD 128
#define NTILES ((NN + 127) / 128)   // 782
#define NB 256                      // phase-A blocks
#define CHUNK (NE / NB)             // 6250
#define NBUCK ((NN + 255) / 256)    // 391 coarse buckets (dst>>8)
#define GH_N (NBUCK * NB)           // 100,096
#define GH_BLK (GH_N / 256)         // 391 scan blocks (exact)

typedef __bf16 bf16x8 __attribute__((ext_vector_type(8)));
typedef float f32x4 __attribute__((ext_vector_type(4)));
typedef float f32x2 __attribute__((ext_vector_type(2)));

// round-to-nearest-even fp32 -> bf16, two at a time, packed into a uint
__device__ __forceinline__ unsigned int f2bf2(float a, float b) {
  union { float f; unsigned u; } x, y;
  x.f = a; y.f = b;
  unsigned ua = x.u + (0x7FFFu + ((x.u >> 16) & 1u));
  unsigned ub = y.u + (0x7FFFu + ((y.u >> 16) & 1u));
  return (ua >> 16) | (ub & 0xFFFF0000u);
}

// ---------------- 0+A1. h (fp32) -> h8 (fp8 e4m3), fused coarse histogram ---
// All 6250 blocks convert 8 elems/thread; blocks < NB additionally histogram
// their 6250-edge chunk (convert is BW-bound with idle VALU/LDS; hist is
// atomic-bound with idle BW -> they overlap instead of serializing).
__global__ __launch_bounds__(256) void convert_hist_kernel(
    const float4* __restrict__ hp, uint2* __restrict__ h8,
    const int* __restrict__ dst, int* __restrict__ gh) {
  __shared__ int lh[NBUCK];
  int gid = blockIdx.x * 256 + threadIdx.x;   // NN*DD/8 = 1.6M threads
  float4 a = hp[2 * gid], b = hp[2 * gid + 1];
  int lo = __builtin_amdgcn_cvt_pk_fp8_f32(a.x, a.y, 0, false);
  lo = __builtin_amdgcn_cvt_pk_fp8_f32(a.z, a.w, lo, true);
  int hi = __builtin_amdgcn_cvt_pk_fp8_f32(b.x, b.y, 0, false);
  hi = __builtin_amdgcn_cvt_pk_fp8_f32(b.z, b.w, hi, true);
  h8[gid] = make_uint2((unsigned)lo, (unsigned)hi);

  if (blockIdx.x < NB) {   // block-uniform branch: __syncthreads inside is safe
    int t = threadIdx.x, bb = blockIdx.x;
    for (int i = t; i < NBUCK; i += 256) lh[i] = 0;
    __syncthreads();
    int e0 = bb * CHUNK;
    for (int e = e0 + t; e < e0 + CHUNK; e += 256)
      atomicAdd(&lh[dst[e] >> 8], 1);
    __syncthreads();
    for (int i = t; i < NBUCK; i += 256) gh[i * NB + bb] = lh[i];
  }
}

// ---------------- A2. hierarchical exclusive scan of gh ---------------------
__global__ __launch_bounds__(256) void blocksum_kernel(const int* __restrict__ gh,
                                                       int* __restrict__ bsum) {
  __shared__ int s[256];
  int t = threadIdx.x;
  s[t] = gh[blockIdx.x * 256 + t];
  __syncthreads();
  for (int d = 128; d > 0; d >>= 1) {
    if (t < d) s[t] += s[t + d];
    __syncthreads();
  }
  if (t == 0) bsum[blockIdx.x] = s[0];
}

__global__ __launch_bounds__(512) void scanbsum_kernel(const int* __restrict__ bsum,
                                                       int* __restrict__ bsum_ex) {
  __shared__ int s[512];
  int t = threadIdx.x;
  int v = (t < GH_BLK) ? bsum[t] : 0;
  s[t] = v;
  __syncthreads();
  for (int d = 1; d < 512; d <<= 1) {
    int x = (t >= d) ? s[t - d] : 0;
    __syncthreads();
    s[t] += x;
    __syncthreads();
  }
  if (t < GH_BLK) bsum_ex[t] = s[t] - v;
}

__global__ __launch_bounds__(256) void scanfull_kernel(const int* __restrict__ gh,
                                                       const int* __restrict__ bsum_ex,
                                                       int* __restrict__ gsc) {
  __shared__ int s[256];
  int t = threadIdx.x;
  int idx = blockIdx.x * 256 + t;
  int v = gh[idx];
  s[t] = v;
  __syncthreads();
  for (int d = 1; d < 256; d <<= 1) {
    int x = (t >= d) ? s[t - d] : 0;
    __syncthreads();
    s[t] += x;
    __syncthreads();
  }
  gsc[idx] = bsum_ex[blockIdx.x] + s[t] - v;
}

// ---------------- A3. coarse scatter, LDS-staged burst writeback ------------
__global__ __launch_bounds__(256) void coarse_scatter_kernel(
    const int* __restrict__ src, const int* __restrict__ dst,
    const int* __restrict__ gsc, unsigned* __restrict__ ebuf) {
  __shared__ int lhpad[512];
  __shared__ int lbase[NBUCK];
  __shared__ int lcur[NBUCK];
  __shared__ int gstart[NBUCK];
  __shared__ unsigned sdata[CHUNK];
  __shared__ int sgpos[CHUNK];
  int t = threadIdx.x, b = blockIdx.x;
  lhpad[t] = 0;
  lhpad[t + 256] = 0;
  __syncthreads();
  int e0 = b * CHUNK;
  for (int e = e0 + t; e < e0 + CHUNK; e += 256)
    atomicAdd(&lhpad[dst[e] >> 8], 1);
  __syncthreads();
  int cnt0 = lhpad[t], cnt1 = lhpad[t + 256];
  for (int d = 1; d < 512; d <<= 1) {
    int x0 = (t >= d) ? lhpad[t - d] : 0;
    int x1 = ((t + 256) >= d) ? lhpad[t + 256 - d] : 0;
    __syncthreads();
    lhpad[t] += x0;
    lhpad[t + 256] += x1;
    __syncthreads();
  }
  if (t < NBUCK) { lbase[t] = lhpad[t] - cnt0; lcur[t] = 0; gstart[t] = gsc[t * NB + b]; }
  int i2 = t + 256;
  if (i2 < NBUCK) { lbase[i2] = lhpad[i2] - cnt1; lcur[i2] = 0; gstart[i2] = gsc[i2 * NB + b]; }
  __syncthreads();
  for (int e = e0 + t; e < e0 + CHUNK; e += 256) {
    int d = dst[e], s = src[e];
    int bk = d >> 8;
    int slot = atomicAdd(&lcur[bk], 1);
    int lp = lbase[bk] + slot;
    sdata[lp] = ((unsigned)(d & 255) << 24) | (unsigned)s;
    sgpos[lp] = gstart[bk] + slot;
  }
  __syncthreads();
  for (int j = t; j < CHUNK; j += 256) ebuf[sgpos[j]] = sdata[j];
}

// ---------------- B. fine sort within bucket -> csr + offs ------------------
__global__ __launch_bounds__(256) void fine_sort_kernel(const unsigned* __restrict__ ebuf,
                                                        const int* __restrict__ gsc,
                                                        int* __restrict__ csr,
                                                        int* __restrict__ offs) {
  __shared__ int hist[256], scn[256], cur[256];
  int t = threadIdx.x, g = blockIdx.x;
  int base = gsc[g * NB];
  int end = (g == NBUCK - 1) ? NE : gsc[(g + 1) * NB];
  hist[t] = 0;
  __syncthreads();
  for (int j = base + t; j < end; j += 256)
    atomicAdd(&hist[ebuf[j] >> 24], 1);
  __syncthreads();
  int v = hist[t];
  scn[t] = v;
  __syncthreads();
  for (int d = 1; d < 256; d <<= 1) {
    int x = (t >= d) ? scn[t - d] : 0;
    __syncthreads();
    scn[t] += x;
    __syncthreads();
  }
  int excl = scn[t] - v;
  int node = g * 256 + t;
  if (node < NN) offs[node] = base + excl;
  if (node == NN - 1) offs[NN] = NE;
  cur[t] = excl;
  __syncthreads();
  for (int j = base + t; j < end; j += 256) {
    unsigned p = ebuf[j];
    int pos = atomicAdd(&cur[p >> 24], 1);
    csr[base + pos] = (int)(p & 0x00FFFFFFu);
  }
}

// ---------------- fp8 accumulate helper -------------------------------------
__device__ __forceinline__ void acc16(float* a, uint4 u) {
  f32x2 p;
  p = __builtin_amdgcn_cvt_pk_f32_fp8(u.x, false); a[0] += p.x;  a[1] += p.y;
  p = __builtin_amdgcn_cvt_pk_f32_fp8(u.x, true);  a[2] += p.x;  a[3] += p.y;
  p = __builtin_amdgcn_cvt_pk_f32_fp8(u.y, false); a[4] += p.x;  a[5] += p.y;
  p = __builtin_amdgcn_cvt_pk_f32_fp8(u.y, true);  a[6] += p.x;  a[7] += p.y;
  p = __builtin_amdgcn_cvt_pk_f32_fp8(u.z, false); a[8] += p.x;  a[9] += p.y;
  p = __builtin_amdgcn_cvt_pk_f32_fp8(u.z, true);  a[10] += p.x; a[11] += p.y;
  p = __builtin_amdgcn_cvt_pk_f32_fp8(u.w, false); a[12] += p.x; a[13] += p.y;
  p = __builtin_amdgcn_cvt_pk_f32_fp8(u.w, true);  a[14] += p.x; a[15] += p.y;
}

// ---------------- staging into fragment-linear LDS --------------------------
__device__ __forceinline__ void stage_f32(const float* __restrict__ X,
                                          int row0, int nvalid,
                                          uint4* buf, int t) {
#pragma unroll
  for (int i = 0; i < 8; i++) {
    int id = t + (i << 8);     // 0..2047
    int r = id >> 4;           // 0..127
    int c8 = id & 15;          // 0..15
    int row = row0 + r;
    float4 v0 = {0.f, 0.f, 0.f, 0.f}, v1 = {0.f, 0.f, 0.f, 0.f};
    if (row < nvalid) {
      const float4* p = (const float4*)(X + (size_t)row * DD + (c8 << 3));
      v0 = p[0];
      v1 = p[1];
    }
    uint4 q;
    q.x = f2bf2(v0.x, v0.y);
    q.y = f2bf2(v0.z, v0.w);
    q.z = f2bf2(v1.x, v1.y);
    q.w = f2bf2(v1.z, v1.w);
    int rt = r >> 4, m = r & 15, kc = c8 >> 2, quad = c8 & 3;
    buf[(((rt << 2) + kc) << 6) + (quad << 4) + m] = q;
  }
}

__device__ __forceinline__ void compute_half(const uint4* sA, const uint4* sW,
                                             f32x4 acc[2][8], int wv, int lane) {
#pragma unroll
  for (int kc = 0; kc < 4; kc++) {
    bf16x8 b[8];
#pragma unroll
    for (int n = 0; n < 8; n++)
      b[n] = *(const bf16x8*)&sW[(((n << 2) + kc) << 6) + lane];
    bf16x8 a0 = *(const bf16x8*)&sA[((((wv * 2 + 0) << 2) + kc) << 6) + lane];
    bf16x8 a1 = *(const bf16x8*)&sA[((((wv * 2 + 1) << 2) + kc) << 6) + lane];
#pragma unroll
    for (int n = 0; n < 8; n++) {
      acc[0][n] = __builtin_amdgcn_mfma_f32_16x16x32_bf16(a0, b[n], acc[0][n], 0, 0, 0);
      acc[1][n] = __builtin_amdgcn_mfma_f32_16x16x32_bf16(a1, b[n], acc[1][n], 0, 0, 0);
    }
  }
}

// ---------------- 5. fused: gather-mean + out = h@Ws^T + hneigh@Wn^T + b ----
// Phase 1: self half (stage h fp32->bf16, MFMA with Wself).
// Phase 2: each 8-lane group gathers+means one node from fp8 h8 and writes the
// bf16 result DIRECTLY into the sA fragment slot (no hneigh round-trip), then
// MFMA with Wneigh. Saves 51.2 MB of HBM traffic + one kernel launch.
__global__ __launch_bounds__(256, 2) void gemm_fused_kernel(
    const float* __restrict__ h, const uint4* __restrict__ h8,
    const int* __restrict__ offs, const int* __restrict__ csr,
    const float* __restrict__ Wself, const float* __restrict__ Wneigh,
    const float* __restrict__ bias, float* __restrict__ out) {
  __shared__ uint4 sA[2048];   // 32 KB
  __shared__ uint4 sW[2048];   // 32 KB  -> 64 KB/block, 2 blocks/CU
  int t = threadIdx.x;
  int wv = t >> 6;
  int lane = t & 63;
  int row0 = blockIdx.x * 128;

  f32x4 acc[2][8];
#pragma unroll
  for (int i = 0; i < 2; i++)
#pragma unroll
    for (int n = 0; n < 8; n++) acc[i][n] = f32x4{0.f, 0.f, 0.f, 0.f};

  // ---- half 1: h @ Wself^T ----
  stage_f32(h, row0, NN, sA, t);
  stage_f32(Wself, 0, 128, sW, t);
  __syncthreads();
  compute_half(sA, sW, acc, wv, lane);
  __syncthreads();   // done reading sA/sW

  // ---- half 2: gather-mean into sA fragments, Wneigh into sW ----
  stage_f32(Wneigh, 0, 128, sW, t);

  int grp = t >> 3;   // 0..31: node group within round
  int l = t & 7;      // 16B fp8 chunk (16 elems) within the 128B row
#pragma unroll 1
  for (int rnd = 0; rnd < 4; rnd++) {
    int r = rnd * 32 + grp;       // row within the 128-row tile
    int q = row0 + r;             // node id
    float a[16];
#pragma unroll
    for (int i = 0; i < 16; i++) a[i] = 0.f;
    float sc = 0.f;
    if (q < NN) {
      int off0 = offs[q], off1 = offs[q + 1];
      int j = off0;
      for (; j + 4 <= off1; j += 4) {
        int s0 = csr[j], s1 = csr[j + 1], s2 = csr[j + 2], s3 = csr[j + 3];
        uint4 u0 = h8[(size_t)s0 * 8 + l];
        uint4 u1 = h8[(size_t)s1 * 8 + l];
        uint4 u2 = h8[(size_t)s2 * 8 + l];
        uint4 u3 = h8[(size_t)s3 * 8 + l];
        acc16(a, u0); acc16(a, u1); acc16(a, u2); acc16(a, u3);
      }
      for (; j < off1; j++) acc16(a, h8[(size_t)csr[j] * 8 + l]);
      int deg = off1 - off0;
      sc = (deg > 0) ? (1.0f / (float)deg) : 0.0f;
    }
    uint4 r0, r1;
    r0.x = f2bf2(a[0] * sc, a[1] * sc);   r0.y = f2bf2(a[2] * sc, a[3] * sc);
    r0.z = f2bf2(a[4] * sc, a[5] * sc);   r0.w = f2bf2(a[6] * sc, a[7] * sc);
    r1.x = f2bf2(a[8] * sc, a[9] * sc);   r1.y = f2bf2(a[10] * sc, a[11] * sc);
    r1.z = f2bf2(a[12] * sc, a[13] * sc); r1.w = f2bf2(a[14] * sc, a[15] * sc);
    // fragment slot for (row r, bf16-chunk c8): rt=r>>4, m=r&15, kc=c8>>2, quad=c8&3
    int rt = r >> 4, m = r & 15;
    int c8a = 2 * l, c8b = 2 * l + 1;
    sA[(((rt << 2) + (c8a >> 2)) << 6) + ((c8a & 3) << 4) + m] = r0;
    sA[(((rt << 2) + (c8b >> 2)) << 6) + ((c8b & 3) << 4) + m] = r1;
  }
  __syncthreads();
  compute_half(sA, sW, acc, wv, lane);

  // epilogue: + bias (C/D layout: col=lane&15, row=(lane>>4)*4+reg)
  int col = lane & 15, rq = lane >> 4;
  float bv[8];
#pragma unroll
  for (int n = 0; n < 8; n++) bv[n] = bias[n * 16 + col];
#pragma unroll
  for (int rt = 0; rt < 2; rt++) {
    int rb = row0 + (wv * 2 + rt) * 16 + rq * 4;
#pragma unroll
    for (int r = 0; r < 4; r++) {
      int row = rb + r;
      if (row < NN) {
        float* op = out + (size_t)row * DD + col;
#pragma unroll
        for (int n = 0; n < 8; n++) op[n * 16] = acc[rt][n][r] + bv[n];
      }
    }
  }
}

extern "C" void kernel_launch(void* const* d_in, const int* in_sizes, int n_in,
                              void* d_out, int out_size, void* d_ws, size_t ws_size,
                              hipStream_t stream) {
  const float* h      = (const float*)d_in[0];
  const int*   src    = (const int*)d_in[1];
  const int*   dst    = (const int*)d_in[2];
  const float* Wself  = (const float*)d_in[3];
  const float* Wneigh = (const float*)d_in[4];
  const float* bias   = (const float*)d_in[5];
  float* out = (float*)d_out;

  // workspace layout (bytes); ebuf region is only live between scatter & sort.
  char* ws = (char*)d_ws;
  unsigned* h8       = (unsigned*)ws;                     // 12,800,000
  unsigned* ebuf     = (unsigned*)(ws + 12800000);        //  6,400,000
  int*      csr      = (int*)(ws + 38400000);             //  6,400,000
  int*      gh       = (int*)(ws + 44800000);             //    400,384
  int*      gsc      = (int*)(ws + 45200384);             //    400,384
  int*      bsum     = (int*)(ws + 45600768);             //      1,568
  int*      bsum_ex  = (int*)(ws + 45602336);             //      1,568
  int*      offs     = (int*)(ws + 45603904);             //    400,016

  convert_hist_kernel<<<6250, 256, 0, stream>>>((const float4*)h, (uint2*)h8, dst, gh);
  blocksum_kernel<<<GH_BLK, 256, 0, stream>>>(gh, bsum);
  scanbsum_kernel<<<1, 512, 0, stream>>>(bsum, bsum_ex);
  scanfull_kernel<<<GH_BLK, 256, 0, stream>>>(gh, bsum_ex, gsc);
  coarse_scatter_kernel<<<NB, 256, 0, stream>>>(src, dst, gsc, ebuf);
  fine_sort_kernel<<<NBUCK, 256, 0, stream>>>(ebuf, gsc, csr, offs);
  gemm_fused_kernel<<<NTILES, 256, 0, stream>>>(h, (const uint4*)h8, offs, csr,
                                                Wself, Wneigh, bias, out);
}

// Round 2
// 224.067 us; speedup vs baseline: 1.0451x; 1.0451x over previous
//
#include <hip/hip_runtime.h>
#include <stdint.h>

#define NN 100000
#define NE 1600000
#define DD 128
#define NTILES ((NN + 127) / 128)   // 782
#define NB 256                      // phase-A blocks
#define CHUNK (NE / NB)             // 6250
#define NBUCK ((NN + 255) / 256)    // 391 coarse buckets (dst>>8)
#define GH_N (NBUCK * NB)           // 100,096
#define GH_BLK (GH_N / 256)         // 391 scan blocks (exact)

typedef __bf16 bf16x8 __attribute__((ext_vector_type(8)));
typedef float f32x4 __attribute__((ext_vector_type(4)));
typedef float f32x2 __attribute__((ext_vector_type(2)));

// round-to-nearest-even fp32 -> bf16, two at a time, packed into a uint
__device__ __forceinline__ unsigned int f2bf2(float a, float b) {
  union { float f; unsigned u; } x, y;
  x.f = a; y.f = b;
  unsigned ua = x.u + (0x7FFFu + ((x.u >> 16) & 1u));
  unsigned ub = y.u + (0x7FFFu + ((y.u >> 16) & 1u));
  return (ua >> 16) | (ub & 0xFFFF0000u);
}

// ---------------- 0+A1. h (fp32) -> h8 (fp8 e4m3), fused coarse histogram ---
__global__ __launch_bounds__(256) void convert_hist_kernel(
    const float4* __restrict__ hp, uint2* __restrict__ h8,
    const int* __restrict__ dst, int* __restrict__ gh) {
  __shared__ int lh[NBUCK];
  int gid = blockIdx.x * 256 + threadIdx.x;   // NN*DD/8 = 1.6M threads
  float4 a = hp[2 * gid], b = hp[2 * gid + 1];
  int lo = __builtin_amdgcn_cvt_pk_fp8_f32(a.x, a.y, 0, false);
  lo = __builtin_amdgcn_cvt_pk_fp8_f32(a.z, a.w, lo, true);
  int hi = __builtin_amdgcn_cvt_pk_fp8_f32(b.x, b.y, 0, false);
  hi = __builtin_amdgcn_cvt_pk_fp8_f32(b.z, b.w, hi, true);
  h8[gid] = make_uint2((unsigned)lo, (unsigned)hi);

  if (blockIdx.x < NB) {   // block-uniform branch: __syncthreads inside is safe
    int t = threadIdx.x, bb = blockIdx.x;
    for (int i = t; i < NBUCK; i += 256) lh[i] = 0;
    __syncthreads();
    int e0 = bb * CHUNK;
    for (int e = e0 + t; e < e0 + CHUNK; e += 256)
      atomicAdd(&lh[dst[e] >> 8], 1);
    __syncthreads();
    for (int i = t; i < NBUCK; i += 256) gh[i * NB + bb] = lh[i];
  }
}

// ---------------- A2. hierarchical exclusive scan of gh ---------------------
__global__ __launch_bounds__(256) void blocksum_kernel(const int* __restrict__ gh,
                                                       int* __restrict__ bsum) {
  __shared__ int s[256];
  int t = threadIdx.x;
  s[t] = gh[blockIdx.x * 256 + t];
  __syncthreads();
  for (int d = 128; d > 0; d >>= 1) {
    if (t < d) s[t] += s[t + d];
    __syncthreads();
  }
  if (t == 0) bsum[blockIdx.x] = s[0];
}

__global__ __launch_bounds__(512) void scanbsum_kernel(const int* __restrict__ bsum,
                                                       int* __restrict__ bsum_ex) {
  __shared__ int s[512];
  int t = threadIdx.x;
  int v = (t < GH_BLK) ? bsum[t] : 0;
  s[t] = v;
  __syncthreads();
  for (int d = 1; d < 512; d <<= 1) {
    int x = (t >= d) ? s[t - d] : 0;
    __syncthreads();
    s[t] += x;
    __syncthreads();
  }
  if (t < GH_BLK) bsum_ex[t] = s[t] - v;
}

__global__ __launch_bounds__(256) void scanfull_kernel(const int* __restrict__ gh,
                                                       const int* __restrict__ bsum_ex,
                                                       int* __restrict__ gsc) {
  __shared__ int s[256];
  int t = threadIdx.x;
  int idx = blockIdx.x * 256 + t;
  int v = gh[idx];
  s[t] = v;
  __syncthreads();
  for (int d = 1; d < 256; d <<= 1) {
    int x = (t >= d) ? s[t - d] : 0;
    __syncthreads();
    s[t] += x;
    __syncthreads();
  }
  gsc[idx] = bsum_ex[blockIdx.x] + s[t] - v;
}

// ---------------- A3. coarse scatter, LDS-staged burst writeback ------------
__global__ __launch_bounds__(256) void coarse_scatter_kernel(
    const int* __restrict__ src, const int* __restrict__ dst,
    const int* __restrict__ gsc, unsigned* __restrict__ ebuf) {
  __shared__ int lhpad[512];
  __shared__ int lbase[NBUCK];
  __shared__ int lcur[NBUCK];
  __shared__ int gstart[NBUCK];
  __shared__ unsigned sdata[CHUNK];
  __shared__ int sgpos[CHUNK];
  int t = threadIdx.x, b = blockIdx.x;
  lhpad[t] = 0;
  lhpad[t + 256] = 0;
  __syncthreads();
  int e0 = b * CHUNK;
  for (int e = e0 + t; e < e0 + CHUNK; e += 256)
    atomicAdd(&lhpad[dst[e] >> 8], 1);
  __syncthreads();
  int cnt0 = lhpad[t], cnt1 = lhpad[t + 256];
  for (int d = 1; d < 512; d <<= 1) {
    int x0 = (t >= d) ? lhpad[t - d] : 0;
    int x1 = ((t + 256) >= d) ? lhpad[t + 256 - d] : 0;
    __syncthreads();
    lhpad[t] += x0;
    lhpad[t + 256] += x1;
    __syncthreads();
  }
  if (t < NBUCK) { lbase[t] = lhpad[t] - cnt0; lcur[t] = 0; gstart[t] = gsc[t * NB + b]; }
  int i2 = t + 256;
  if (i2 < NBUCK) { lbase[i2] = lhpad[i2] - cnt1; lcur[i2] = 0; gstart[i2] = gsc[i2 * NB + b]; }
  __syncthreads();
  for (int e = e0 + t; e < e0 + CHUNK; e += 256) {
    int d = dst[e], s = src[e];
    int bk = d >> 8;
    int slot = atomicAdd(&lcur[bk], 1);
    int lp = lbase[bk] + slot;
    sdata[lp] = ((unsigned)(d & 255) << 24) | (unsigned)s;
    sgpos[lp] = gstart[bk] + slot;
  }
  __syncthreads();
  for (int j = t; j < CHUNK; j += 256) ebuf[sgpos[j]] = sdata[j];
}

// ---------------- B. fine sort within bucket -> csr + offs ------------------
__global__ __launch_bounds__(256) void fine_sort_kernel(const unsigned* __restrict__ ebuf,
                                                        const int* __restrict__ gsc,
                                                        int* __restrict__ csr,
                                                        int* __restrict__ offs) {
  __shared__ int hist[256], scn[256], cur[256];
  int t = threadIdx.x, g = blockIdx.x;
  int base = gsc[g * NB];
  int end = (g == NBUCK - 1) ? NE : gsc[(g + 1) * NB];
  hist[t] = 0;
  __syncthreads();
  for (int j = base + t; j < end; j += 256)
    atomicAdd(&hist[ebuf[j] >> 24], 1);
  __syncthreads();
  int v = hist[t];
  scn[t] = v;
  __syncthreads();
  for (int d = 1; d < 256; d <<= 1) {
    int x = (t >= d) ? scn[t - d] : 0;
    __syncthreads();
    scn[t] += x;
    __syncthreads();
  }
  int excl = scn[t] - v;
  int node = g * 256 + t;
  if (node < NN) offs[node] = base + excl;
  if (node == NN - 1) offs[NN] = NE;
  cur[t] = excl;
  __syncthreads();
  for (int j = base + t; j < end; j += 256) {
    unsigned p = ebuf[j];
    int pos = atomicAdd(&cur[p >> 24], 1);
    csr[base + pos] = (int)(p & 0x00FFFFFFu);
  }
}

// ---------------- fp8 accumulate helper -------------------------------------
__device__ __forceinline__ void acc16(float* a, uint4 u) {
  f32x2 p;
  p = __builtin_amdgcn_cvt_pk_f32_fp8(u.x, false); a[0] += p.x;  a[1] += p.y;
  p = __builtin_amdgcn_cvt_pk_f32_fp8(u.x, true);  a[2] += p.x;  a[3] += p.y;
  p = __builtin_amdgcn_cvt_pk_f32_fp8(u.y, false); a[4] += p.x;  a[5] += p.y;
  p = __builtin_amdgcn_cvt_pk_f32_fp8(u.y, true);  a[6] += p.x;  a[7] += p.y;
  p = __builtin_amdgcn_cvt_pk_f32_fp8(u.z, false); a[8] += p.x;  a[9] += p.y;
  p = __builtin_amdgcn_cvt_pk_f32_fp8(u.z, true);  a[10] += p.x; a[11] += p.y;
  p = __builtin_amdgcn_cvt_pk_f32_fp8(u.w, false); a[12] += p.x; a[13] += p.y;
  p = __builtin_amdgcn_cvt_pk_f32_fp8(u.w, true);  a[14] += p.x; a[15] += p.y;
}

// ---------------- 4. gather-mean -> bf16 in MFMA-fragment-linear order ------
// One node per 8 lanes; fp8 row = 128 B = 8 lanes x uint4. Output for node q
// (tile = q>>7, r = q&127) goes directly to the fragment slot the GEMM's
// wave/lane will load: d = (((rt<<2)+kc)<<6) + (quad<<4) + m  (uint4 index).
// High occupancy (no LDS, ~64 VGPR) gives the latency hiding the fused
// version lost.
__global__ __launch_bounds__(256) void gather_frag_kernel(
    const uint4* __restrict__ h8, const int* __restrict__ offs,
    const int* __restrict__ csr, uint4* __restrict__ hfrag) {
  int q = (blockIdx.x * 256 + threadIdx.x) >> 3;   // 0 .. NTILES*128-1 (exact)
  int l = threadIdx.x & 7;                         // 16B chunk within fp8 row
  float a[16];
#pragma unroll
  for (int i = 0; i < 16; i++) a[i] = 0.f;
  float sc = 0.f;
  if (q < NN) {
    int off0 = offs[q], off1 = offs[q + 1];
    int j = off0;
    for (; j + 4 <= off1; j += 4) {
      int s0 = csr[j], s1 = csr[j + 1], s2 = csr[j + 2], s3 = csr[j + 3];
      uint4 u0 = h8[(size_t)s0 * 8 + l];
      uint4 u1 = h8[(size_t)s1 * 8 + l];
      uint4 u2 = h8[(size_t)s2 * 8 + l];
      uint4 u3 = h8[(size_t)s3 * 8 + l];
      acc16(a, u0); acc16(a, u1); acc16(a, u2); acc16(a, u3);
    }
    for (; j < off1; j++) acc16(a, h8[(size_t)csr[j] * 8 + l]);
    int deg = off1 - off0;
    sc = (deg > 0) ? (1.0f / (float)deg) : 0.0f;
  }
  uint4 r0, r1;
  r0.x = f2bf2(a[0] * sc, a[1] * sc);   r0.y = f2bf2(a[2] * sc, a[3] * sc);
  r0.z = f2bf2(a[4] * sc, a[5] * sc);   r0.w = f2bf2(a[6] * sc, a[7] * sc);
  r1.x = f2bf2(a[8] * sc, a[9] * sc);   r1.y = f2bf2(a[10] * sc, a[11] * sc);
  r1.z = f2bf2(a[12] * sc, a[13] * sc); r1.w = f2bf2(a[14] * sc, a[15] * sc);
  // fragment slot: c8a = 2l, c8b = 2l+1 share kc = l>>1; quads 2(l&1), 2(l&1)+1
  int r = q & 127;
  int rt = r >> 4, m = r & 15;
  int kc = l >> 1, quad = (l & 1) << 1;
  int slot = (((rt << 2) + kc) << 6) + (quad << 4) + m;
  uint4* base = hfrag + (size_t)(q >> 7) * 2048;
  base[slot] = r0;
  base[slot + 16] = r1;
}

// ---------------- staging into fragment-linear LDS --------------------------
__device__ __forceinline__ void stage_f32(const float* __restrict__ X,
                                          int row0, int nvalid,
                                          uint4* buf, int t) {
#pragma unroll
  for (int i = 0; i < 8; i++) {
    int id = t + (i << 8);     // 0..2047
    int r = id >> 4;           // 0..127
    int c8 = id & 15;          // 0..15
    int row = row0 + r;
    float4 v0 = {0.f, 0.f, 0.f, 0.f}, v1 = {0.f, 0.f, 0.f, 0.f};
    if (row < nvalid) {
      const float4* p = (const float4*)(X + (size_t)row * DD + (c8 << 3));
      v0 = p[0];
      v1 = p[1];
    }
    uint4 q;
    q.x = f2bf2(v0.x, v0.y);
    q.y = f2bf2(v0.z, v0.w);
    q.z = f2bf2(v1.x, v1.y);
    q.w = f2bf2(v1.z, v1.w);
    int rt = r >> 4, m = r & 15, kc = c8 >> 2, quad = c8 & 3;
    buf[(((rt << 2) + kc) << 6) + (quad << 4) + m] = q;
  }
}

__device__ __forceinline__ void compute_half(const uint4* sA, const uint4* sW,
                                             f32x4 acc[2][8], int wv, int lane) {
#pragma unroll
  for (int kc = 0; kc < 4; kc++) {
    bf16x8 b[8];
#pragma unroll
    for (int n = 0; n < 8; n++)
      b[n] = *(const bf16x8*)&sW[(((n << 2) + kc) << 6) + lane];
    bf16x8 a0 = *(const bf16x8*)&sA[((((wv * 2 + 0) << 2) + kc) << 6) + lane];
    bf16x8 a1 = *(const bf16x8*)&sA[((((wv * 2 + 1) << 2) + kc) << 6) + lane];
#pragma unroll
    for (int n = 0; n < 8; n++) {
      acc[0][n] = __builtin_amdgcn_mfma_f32_16x16x32_bf16(a0, b[n], acc[0][n], 0, 0, 0);
      acc[1][n] = __builtin_amdgcn_mfma_f32_16x16x32_bf16(a1, b[n], acc[1][n], 0, 0, 0);
    }
  }
}

// ---------------- 5. out = h@Ws^T + hneigh@Wn^T + b -------------------------
// A2 fragments prefetched global->register at kernel start (coalesced uint4
// loads from the fragment-ordered hfrag); their latency hides under h staging
// + the self-half MFMAs. No LDS pass for A2 at all.
__global__ __launch_bounds__(256, 2) void gemm_kernel(
    const float* __restrict__ h, const uint4* __restrict__ hfrag,
    const float* __restrict__ Wself, const float* __restrict__ Wneigh,
    const float* __restrict__ bias, float* __restrict__ out) {
  __shared__ uint4 sA[2048];   // 32 KB
  __shared__ uint4 sW[2048];   // 32 KB
  int t = threadIdx.x;
  int wv = t >> 6;
  int lane = t & 63;
  int row0 = blockIdx.x * 128;

  // prefetch half-2 A fragments (8 x 16B per thread, fully coalesced)
  const uint4* fb = hfrag + (size_t)blockIdx.x * 2048;
  uint4 a2[8];
#pragma unroll
  for (int kc = 0; kc < 4; kc++) {
    a2[kc]     = fb[((((wv * 2 + 0) << 2) + kc) << 6) + lane];
    a2[4 + kc] = fb[((((wv * 2 + 1) << 2) + kc) << 6) + lane];
  }

  f32x4 acc[2][8];
#pragma unroll
  for (int i = 0; i < 2; i++)
#pragma unroll
    for (int n = 0; n < 8; n++) acc[i][n] = f32x4{0.f, 0.f, 0.f, 0.f};

  // ---- half 1: h @ Wself^T ----
  stage_f32(h, row0, NN, sA, t);
  stage_f32(Wself, 0, 128, sW, t);
  __syncthreads();
  compute_half(sA, sW, acc, wv, lane);
  __syncthreads();   // done reading sW

  // ---- half 2: hneigh (registers) @ Wneigh^T ----
  stage_f32(Wneigh, 0, 128, sW, t);
  __syncthreads();
#pragma unroll
  for (int kc = 0; kc < 4; kc++) {
    bf16x8 b[8];
#pragma unroll
    for (int n = 0; n < 8; n++)
      b[n] = *(const bf16x8*)&sW[(((n << 2) + kc) << 6) + lane];
    bf16x8 a0 = *(const bf16x8*)&a2[kc];
    bf16x8 a1 = *(const bf16x8*)&a2[4 + kc];
#pragma unroll
    for (int n = 0; n < 8; n++) {
      acc[0][n] = __builtin_amdgcn_mfma_f32_16x16x32_bf16(a0, b[n], acc[0][n], 0, 0, 0);
      acc[1][n] = __builtin_amdgcn_mfma_f32_16x16x32_bf16(a1, b[n], acc[1][n], 0, 0, 0);
    }
  }

  // epilogue: + bias (C/D layout: col=lane&15, row=(lane>>4)*4+reg)
  int col = lane & 15, rq = lane >> 4;
  float bv[8];
#pragma unroll
  for (int n = 0; n < 8; n++) bv[n] = bias[n * 16 + col];
#pragma unroll
  for (int rt = 0; rt < 2; rt++) {
    int rb = row0 + (wv * 2 + rt) * 16 + rq * 4;
#pragma unroll
    for (int r = 0; r < 4; r++) {
      int row = rb + r;
      if (row < NN) {
        float* op = out + (size_t)row * DD + col;
#pragma unroll
        for (int n = 0; n < 8; n++) op[n * 16] = acc[rt][n][r] + bv[n];
      }
    }
  }
}

extern "C" void kernel_launch(void* const* d_in, const int* in_sizes, int n_in,
                              void* d_out, int out_size, void* d_ws, size_t ws_size,
                              hipStream_t stream) {
  const float* h      = (const float*)d_in[0];
  const int*   src    = (const int*)d_in[1];
  const int*   dst    = (const int*)d_in[2];
  const float* Wself  = (const float*)d_in[3];
  const float* Wneigh = (const float*)d_in[4];
  const float* bias   = (const float*)d_in[5];
  float* out = (float*)d_out;

  // workspace layout (bytes); ebuf aliases hfrag head (dead before gather).
  // Peak footprint: ~46.03 MB.
  char* ws = (char*)d_ws;
  unsigned* h8       = (unsigned*)ws;                     // 12,800,000
  unsigned* hfrag    = (unsigned*)(ws + 12800000);        // 25,624,576 (782*32768)
  unsigned* ebuf     = (unsigned*)(ws + 12800000);        //  6,400,000 (alias)
  int*      csr      = (int*)(ws + 38425600);             //  6,400,000
  int*      gh       = (int*)(ws + 44825600);             //    400,384
  int*      gsc      = (int*)(ws + 45225984);             //    400,384
  int*      bsum     = (int*)(ws + 45626368);             //      1,568
  int*      bsum_ex  = (int*)(ws + 45627936);             //      1,568
  int*      offs     = (int*)(ws + 45629504);             //    400,016

  convert_hist_kernel<<<6250, 256, 0, stream>>>((const float4*)h, (uint2*)h8, dst, gh);
  blocksum_kernel<<<GH_BLK, 256, 0, stream>>>(gh, bsum);
  scanbsum_kernel<<<1, 512, 0, stream>>>(bsum, bsum_ex);
  scanfull_kernel<<<GH_BLK, 256, 0, stream>>>(gh, bsum_ex, gsc);
  coarse_scatter_kernel<<<NB, 256, 0, stream>>>(src, dst, gsc, ebuf);
  fine_sort_kernel<<<NBUCK, 256, 0, stream>>>(ebuf, gsc, csr, offs);
  gather_frag_kernel<<<(NTILES * 128) / 32, 256, 0, stream>>>(
      (const uint4*)h8, offs, csr, (uint4*)hfrag);
  gemm_kernel<<<NTILES, 256, 0, stream>>>(h, (const uint4*)hfrag,
                                          Wself, Wneigh, bias, out);
}